// Round 5
// baseline (246.891 us; speedup 1.0000x reference)
//
#include <hip/hip_runtime.h>

#define Bn 32
#define Cn 3
#define Hn 512
#define Wn 512
#define HWn (Hn * Wn)
#define RBLK 16   // reduce blocks per batch

// FOV = 0.3125*512 = 160 exactly; K = 0.208*512 = 106.496
#define FOVc 160.0f
#define Kc   106.496f

// ---------------- Pass 1: per-batch partial reductions (no atomics, no memset) ----
// ws[b*RBLK + blk] = {sum S, sum S*r, sum S*r^2, max r} for this block
__global__ __launch_bounds__(256) void reduce_k(const float4* __restrict__ sal,
                                                const float* __restrict__ gaze,
                                                float4* __restrict__ ws) {
    const int b = blockIdx.y;
    const float xg = gaze[2 * b + 0];
    const float yg = gaze[2 * b + 1];
    const int tid = threadIdx.x;
    const int idx0 = blockIdx.x * 256 + tid;           // float4 index within batch
    const float4* sb = sal + (size_t)b * (HWn / 4);

    float sumS = 0.0f, sumSr = 0.0f, sumSr2 = 0.0f, rmax = 0.0f;

    for (int i = idx0; i < HWn / 4; i += RBLK * 256) {
        float4 s4 = sb[i];
        const int pix = i * 4;
        const float y = (float)(pix >> 9);
        const float xbase = (float)(pix & 511);
        const float dy = y - yg;
        const float dy2 = dy * dy + 1e-6f;
        const float sv[4] = {s4.x, s4.y, s4.z, s4.w};
#pragma unroll
        for (int j = 0; j < 4; ++j) {
            const float dx = xbase + (float)j - xg;
            const float r = sqrtf(dx * dx + dy2);
            const float s = sv[j];
            sumS   += s;
            sumSr  += s * r;
            sumSr2 += s * r * r;
            rmax = fmaxf(rmax, r);
        }
    }

    // wave (64-lane) butterfly reduce
#pragma unroll
    for (int off = 32; off > 0; off >>= 1) {
        sumS   += __shfl_down(sumS, off);
        sumSr  += __shfl_down(sumSr, off);
        sumSr2 += __shfl_down(sumSr2, off);
        rmax = fmaxf(rmax, __shfl_down(rmax, off));
    }

    __shared__ float red[4][4];
    const int wave = tid >> 6, lane = tid & 63;
    if (lane == 0) {
        red[wave][0] = sumS; red[wave][1] = sumSr; red[wave][2] = sumSr2; red[wave][3] = rmax;
    }
    __syncthreads();
    if (tid == 0) {
        float a = 0, c = 0, d = 0, m = 0;
        for (int w = 0; w < 4; ++w) {
            a += red[w][0]; c += red[w][1]; d += red[w][2]; m = fmaxf(m, red[w][3]);
        }
        ws[b * RBLK + blockIdx.x] = make_float4(a, c, d, m);
    }
}

// ---------------- Pass 2: collapse partials -> {fov_eff, coef} per batch ----------
// writes ws[Bn*RBLK + b] = (fov_eff, coef, 0, 0)
__global__ void finalize_k(float4* __restrict__ ws) {
    const int b = threadIdx.x;
    if (b >= Bn) return;
    float sumS = 0.0f, sumSr = 0.0f, sumSr2 = 0.0f, rmax = 0.0f;
#pragma unroll
    for (int k = 0; k < RBLK; ++k) {
        const float4 p = ws[b * RBLK + k];
        sumS += p.x; sumSr += p.y; sumSr2 += p.z; rmax = fmaxf(rmax, p.w);
    }
    const float inv = 1.0f / (sumS + 1e-6f);
    const float mean_r  = sumSr * inv;
    const float mean_r2 = sumSr2 * inv;
    const float var_r = fmaxf(mean_r2 - mean_r * mean_r, 0.0f);
    const float spread = sqrtf(var_r) / rmax;
    const float fov_eff = FOVc * (1.0f + 0.5f * spread);
    float tmax;
    if (rmax < fov_eff) {
        tmax = rmax;
    } else {
        const float rk = rmax + Kc;
        tmax = rk * rk / (2.0f * (fov_eff + Kc)) + (fov_eff - Kc) * 0.5f;
    }
    const float coef = rmax / (tmax + 1e-6f);
    ws[Bn * RBLK + b] = make_float4(fov_eff, coef, 0.0f, 0.0f);
}

// ---------------- Pass 3: warp + bilinear sample + uint8 truncate, 1 px/thread,
//                  32x8 2D tiles (compact gather footprint), NT stores (keep img in L2)
__global__ __launch_bounds__(256) void sample_k(const float* __restrict__ img,
                                                const float* __restrict__ gaze,
                                                const float4* __restrict__ ws,
                                                int* __restrict__ out) {
    const int b = blockIdx.z;

    // uniform per-batch scalars (4 scalar loads + a few SALU/VALU ops)
    const float4 fc = ws[Bn * RBLK + b];
    const float fov_eff = fc.x;
    const float coef    = fc.y;
    const float xg = gaze[2 * b + 0];
    const float yg = gaze[2 * b + 1];
    const float inv2fk = 0.5f / (fov_eff + Kc);      // r_peri = (r+K)^2 * inv2fk + addc
    const float addc   = (fov_eff - Kc) * 0.5f;

    // 2D tile mapping: block covers 32x8 pixels
    const int tx = threadIdx.x & 31;
    const int ty = threadIdx.x >> 5;
    const int xi = blockIdx.x * 32 + tx;
    const int yi = blockIdx.y * 8 + ty;
    const int pix = yi * Wn + xi;

    const float dx = (float)xi - xg;
    const float dy = (float)yi - yg;
    const float d2 = dx * dx + dy * dy + 1e-6f;
    const float inv_r = __builtin_amdgcn_rsqf(d2);   // ~1ulp
    const float r = d2 * inv_r;                       // = sqrt(d2)

    const float rk = r + Kc;
    const float r_peri = rk * rk * inv2fk + addc;
    const float r_tfm = (r < fov_eff) ? r : r_peri;
    const float scale = coef * r_tfm * inv_r;        // r_new / r

    const float X = xg + dx * scale;
    const float Y = yg + dy * scale;

    const float x0f = floorf(X), y0f = floorf(Y);
    const float x1f = x0f + 1.0f, y1f = y0f + 1.0f;
    const float wx1 = X - x0f, wx0 = 1.0f - wx1;
    const float wy1 = Y - y0f, wy0 = 1.0f - wy1;

    const bool vx0 = (x0f >= 0.0f) & (x0f <= 511.0f);
    const bool vx1 = (x1f >= 0.0f) & (x1f <= 511.0f);
    const bool vy0 = (y0f >= 0.0f) & (y0f <= 511.0f);
    const bool vy1 = (y1f >= 0.0f) & (y1f <= 511.0f);

    const int xc0 = (int)fminf(fmaxf(x0f, 0.0f), 511.0f);
    const int xc1 = (int)fminf(fmaxf(x1f, 0.0f), 511.0f);
    const int yc0 = (int)fminf(fmaxf(y0f, 0.0f), 511.0f);
    const int yc1 = (int)fminf(fmaxf(y1f, 0.0f), 511.0f);

    const float w00 = wy0 * wx0 * ((vy0 & vx0) ? 1.0f : 0.0f);
    const float w01 = wy0 * wx1 * ((vy0 & vx1) ? 1.0f : 0.0f);
    const float w10 = wy1 * wx0 * ((vy1 & vx0) ? 1.0f : 0.0f);
    const float w11 = wy1 * wx1 * ((vy1 & vx1) ? 1.0f : 0.0f);

    const int o00 = yc0 * Wn + xc0;
    const int o01 = yc0 * Wn + xc1;
    const int o10 = yc1 * Wn + xc0;
    const int o11 = yc1 * Wn + xc1;

    const float* ib = img + (size_t)b * Cn * HWn;
#pragma unroll
    for (int c = 0; c < Cn; ++c) {
        const float* p = ib + (size_t)c * HWn;
        float v = p[o00] * w00 + p[o01] * w01 + p[o10] * w10 + p[o11] * w11;
        v = fminf(fmaxf(v, 0.0f), 255.0f);
        // uint8 truncation; harness reads d_out as int32. Non-temporal: output
        // is never re-read — keeps the write stream from evicting img in L2.
        __builtin_nontemporal_store((int)v, &out[((size_t)b * Cn + c) * HWn + pix]);
    }
}

extern "C" void kernel_launch(void* const* d_in, const int* in_sizes, int n_in,
                              void* d_out, int out_size, void* d_ws, size_t ws_size,
                              hipStream_t stream) {
    const float* img  = (const float*)d_in[0];
    const float* gaze = (const float*)d_in[1];
    const float* sal  = (const float*)d_in[2];
    int* out   = (int*)d_out;
    float4* ws = (float4*)d_ws;

    reduce_k<<<dim3(RBLK, Bn), 256, 0, stream>>>((const float4*)sal, gaze, ws);
    finalize_k<<<1, 32, 0, stream>>>(ws);
    sample_k<<<dim3(Wn / 32, Hn / 8, Bn), 256, 0, stream>>>(img, gaze, ws, out);
}

// Round 6
// 244.497 us; speedup vs baseline: 1.0098x; 1.0098x over previous
//
#include <hip/hip_runtime.h>

#define Bn 32
#define Cn 3
#define Hn 512
#define Wn 512
#define HWn (Hn * Wn)
#define RBLK 16   // reduce blocks per batch

// FOV = 0.3125*512 = 160 exactly; K = 0.208*512 = 106.496
#define FOVc 160.0f
#define Kc   106.496f

// ---------------- Pass 1: per-batch partial reductions (no atomics, no memset) ----
// ws[b*RBLK + blk] = {sum S, sum S*r, sum S*r^2, max r} for this block
__global__ __launch_bounds__(256) void reduce_k(const float4* __restrict__ sal,
                                                const float* __restrict__ gaze,
                                                float4* __restrict__ ws) {
    const int b = blockIdx.y;
    const float xg = gaze[2 * b + 0];
    const float yg = gaze[2 * b + 1];
    const int tid = threadIdx.x;
    const int idx0 = blockIdx.x * 256 + tid;           // float4 index within batch
    const float4* sb = sal + (size_t)b * (HWn / 4);

    float sumS = 0.0f, sumSr = 0.0f, sumSr2 = 0.0f, rmax = 0.0f;

    for (int i = idx0; i < HWn / 4; i += RBLK * 256) {
        float4 s4 = sb[i];
        const int pix = i * 4;
        const float y = (float)(pix >> 9);
        const float xbase = (float)(pix & 511);
        const float dy = y - yg;
        const float dy2 = dy * dy + 1e-6f;
        const float sv[4] = {s4.x, s4.y, s4.z, s4.w};
#pragma unroll
        for (int j = 0; j < 4; ++j) {
            const float dx = xbase + (float)j - xg;
            const float r = sqrtf(dx * dx + dy2);
            const float s = sv[j];
            sumS   += s;
            sumSr  += s * r;
            sumSr2 += s * r * r;
            rmax = fmaxf(rmax, r);
        }
    }

    // wave (64-lane) butterfly reduce
#pragma unroll
    for (int off = 32; off > 0; off >>= 1) {
        sumS   += __shfl_down(sumS, off);
        sumSr  += __shfl_down(sumSr, off);
        sumSr2 += __shfl_down(sumSr2, off);
        rmax = fmaxf(rmax, __shfl_down(rmax, off));
    }

    __shared__ float red[4][4];
    const int wave = tid >> 6, lane = tid & 63;
    if (lane == 0) {
        red[wave][0] = sumS; red[wave][1] = sumSr; red[wave][2] = sumSr2; red[wave][3] = rmax;
    }
    __syncthreads();
    if (tid == 0) {
        float a = 0, c = 0, d = 0, m = 0;
        for (int w = 0; w < 4; ++w) {
            a += red[w][0]; c += red[w][1]; d += red[w][2]; m = fmaxf(m, red[w][3]);
        }
        ws[b * RBLK + blockIdx.x] = make_float4(a, c, d, m);
    }
}

// ---------------- Pass 2: collapse partials -> {fov_eff, coef} per batch ----------
// writes ws[Bn*RBLK + b] = (fov_eff, coef, 0, 0)
__global__ void finalize_k(float4* __restrict__ ws) {
    const int b = threadIdx.x;
    if (b >= Bn) return;
    float sumS = 0.0f, sumSr = 0.0f, sumSr2 = 0.0f, rmax = 0.0f;
#pragma unroll
    for (int k = 0; k < RBLK; ++k) {
        const float4 p = ws[b * RBLK + k];
        sumS += p.x; sumSr += p.y; sumSr2 += p.z; rmax = fmaxf(rmax, p.w);
    }
    const float inv = 1.0f / (sumS + 1e-6f);
    const float mean_r  = sumSr * inv;
    const float mean_r2 = sumSr2 * inv;
    const float var_r = fmaxf(mean_r2 - mean_r * mean_r, 0.0f);
    const float spread = sqrtf(var_r) / rmax;
    const float fov_eff = FOVc * (1.0f + 0.5f * spread);
    float tmax;
    if (rmax < fov_eff) {
        tmax = rmax;
    } else {
        const float rk = rmax + Kc;
        tmax = rk * rk / (2.0f * (fov_eff + Kc)) + (fov_eff - Kc) * 0.5f;
    }
    const float coef = rmax / (tmax + 1e-6f);
    ws[Bn * RBLK + b] = make_float4(fov_eff, coef, 0.0f, 0.0f);
}

// ---------------- Pass 3: warp + bilinear sample + uint8 truncate, 1 px/thread.
// 64x4 tiles: each wave = one full 64-px row segment -> uniform dy per wave and
// fully-coalesced 256B stores. Normal (cached) stores — NT stores extended wave
// lifetime (retire waits on HBM write queue) and cost occupancy in R4/R5.
__global__ __launch_bounds__(256) void sample_k(const float* __restrict__ img,
                                                const float* __restrict__ gaze,
                                                const float4* __restrict__ ws,
                                                int* __restrict__ out) {
    const int b = blockIdx.z;

    // uniform per-batch scalars (scalar loads + a few ops)
    const float4 fc = ws[Bn * RBLK + b];
    const float fov_eff = fc.x;
    const float coef    = fc.y;
    const float xg = gaze[2 * b + 0];
    const float yg = gaze[2 * b + 1];
    const float inv2fk = 0.5f / (fov_eff + Kc);      // r_peri = (r+K)^2 * inv2fk + addc
    const float addc   = (fov_eff - Kc) * 0.5f;

    // 2D tile mapping: block covers 64x4 pixels
    const int tx = threadIdx.x & 63;
    const int ty = threadIdx.x >> 6;
    const int xi = blockIdx.x * 64 + tx;
    const int yi = blockIdx.y * 4 + ty;
    const int pix = yi * Wn + xi;

    const float dx = (float)xi - xg;
    const float dy = (float)yi - yg;
    const float d2 = dx * dx + dy * dy + 1e-6f;
    const float inv_r = __builtin_amdgcn_rsqf(d2);   // ~1ulp
    const float r = d2 * inv_r;                       // = sqrt(d2)

    const float rk = r + Kc;
    const float r_peri = rk * rk * inv2fk + addc;
    const float r_tfm = (r < fov_eff) ? r : r_peri;
    const float scale = coef * r_tfm * inv_r;        // r_new / r

    const float X = xg + dx * scale;
    const float Y = yg + dy * scale;

    const float x0f = floorf(X), y0f = floorf(Y);
    const float x1f = x0f + 1.0f, y1f = y0f + 1.0f;
    const float wx1 = X - x0f, wx0 = 1.0f - wx1;
    const float wy1 = Y - y0f, wy0 = 1.0f - wy1;

    const bool vx0 = (x0f >= 0.0f) & (x0f <= 511.0f);
    const bool vx1 = (x1f >= 0.0f) & (x1f <= 511.0f);
    const bool vy0 = (y0f >= 0.0f) & (y0f <= 511.0f);
    const bool vy1 = (y1f >= 0.0f) & (y1f <= 511.0f);

    const int xc0 = (int)fminf(fmaxf(x0f, 0.0f), 511.0f);
    const int xc1 = (int)fminf(fmaxf(x1f, 0.0f), 511.0f);
    const int yc0 = (int)fminf(fmaxf(y0f, 0.0f), 511.0f);
    const int yc1 = (int)fminf(fmaxf(y1f, 0.0f), 511.0f);

    const float w00 = wy0 * wx0 * ((vy0 & vx0) ? 1.0f : 0.0f);
    const float w01 = wy0 * wx1 * ((vy0 & vx1) ? 1.0f : 0.0f);
    const float w10 = wy1 * wx0 * ((vy1 & vx0) ? 1.0f : 0.0f);
    const float w11 = wy1 * wx1 * ((vy1 & vx1) ? 1.0f : 0.0f);

    const int o00 = yc0 * Wn + xc0;
    const int o01 = yc0 * Wn + xc1;
    const int o10 = yc1 * Wn + xc0;
    const int o11 = yc1 * Wn + xc1;

    const float* ib = img + (size_t)b * Cn * HWn;
#pragma unroll
    for (int c = 0; c < Cn; ++c) {
        const float* p = ib + (size_t)c * HWn;
        float v = p[o00] * w00 + p[o01] * w01 + p[o10] * w10 + p[o11] * w11;
        v = fminf(fmaxf(v, 0.0f), 255.0f);
        out[((size_t)b * Cn + c) * HWn + pix] = (int)v;   // uint8 truncation, int32 buffer
    }
}

extern "C" void kernel_launch(void* const* d_in, const int* in_sizes, int n_in,
                              void* d_out, int out_size, void* d_ws, size_t ws_size,
                              hipStream_t stream) {
    const float* img  = (const float*)d_in[0];
    const float* gaze = (const float*)d_in[1];
    const float* sal  = (const float*)d_in[2];
    int* out   = (int*)d_out;
    float4* ws = (float4*)d_ws;

    reduce_k<<<dim3(RBLK, Bn), 256, 0, stream>>>((const float4*)sal, gaze, ws);
    finalize_k<<<1, 32, 0, stream>>>(ws);
    sample_k<<<dim3(Wn / 64, Hn / 4, Bn), 256, 0, stream>>>(img, gaze, ws, out);
}